// Round 3
// baseline (405.796 us; speedup 1.0000x reference)
//
#include <hip/hip_runtime.h>
#include <hip/hip_bf16.h>

#define NT 1024     // tokens (B*S)
#define HD 1024     // hidden
#define ED 1024     // expert inner dim
#define F2D 2048    // 2*E (interleaved gate/up)
#define NEXPERT 16
#define GROWS 2304  // compacted rows (2048) + tile slack
#define ALPHA_C 1.702f
#define LIMIT_C 7.0f

typedef float f32x4 __attribute__((ext_vector_type(4)));
typedef short short8 __attribute__((ext_vector_type(8)));

__device__ __forceinline__ unsigned short f2bf(float x) {
  union { float f; unsigned int u; } v; v.f = x;
  unsigned int r = v.u + 0x7FFFu + ((v.u >> 16) & 1u);
  return (unsigned short)(r >> 16);
}
__device__ __forceinline__ unsigned int pk2(float lo, float hi) {
  return (unsigned int)f2bf(lo) | ((unsigned int)f2bf(hi) << 16);
}

// ---------------- router: fp32 logits, top-2, softmax; x->bf16; out = w0*bd[e0]+w1*bd[e1] ----------------
__global__ __launch_bounds__(64) void k_router(const float* __restrict__ x,
                                               const float* __restrict__ Wg,
                                               const float* __restrict__ bg,
                                               const float* __restrict__ bd,
                                               int* __restrict__ e01,
                                               float* __restrict__ w0f,
                                               float* __restrict__ w1f,
                                               unsigned short* __restrict__ Xbf,
                                               float* __restrict__ out) {
  const int t = blockIdx.x;
  const int l = threadIdx.x;
  const float4* x4 = (const float4*)(x + (size_t)t * HD);
  for (int i = 0; i < 4; ++i) {
    const int idx = l + 64 * i;
    float4 v = x4[idx];
    unsigned int a = pk2(v.x, v.y);
    unsigned int b = pk2(v.z, v.w);
    unsigned int* dst = (unsigned int*)(Xbf + (size_t)t * HD + idx * 4);
    dst[0] = a; dst[1] = b;
  }
  // logits: lane -> (expert = l&15, quarter = l>>4)
  const int e = l & 15, qq = l >> 4;
  const float4* wg4 = (const float4*)(Wg + (size_t)e * HD);
  float s = 0.f;
  for (int j = 0; j < 64; ++j) {
    const int idx = qq + 4 * j;
    float4 a = x4[idx], b = wg4[idx];
    s += a.x * b.x + a.y * b.y + a.z * b.z + a.w * b.w;
  }
  s += __shfl_xor(s, 16);
  s += __shfl_xor(s, 32);
  const float logit = s + bg[e];  // valid in lanes 0..15
  // top-2 (strict > keeps lowest index, matching jax.lax.top_k tie-break)
  float v0 = -1e30f, v1 = -1e30f; int i0 = 0, i1 = 0;
  for (int k = 0; k < 16; ++k) {
    float lv = __shfl(logit, k);
    if (lv > v0) { v1 = v0; i1 = i0; v0 = lv; i0 = k; }
    else if (lv > v1) { v1 = lv; i1 = k; }
  }
  const float w0 = 1.f / (1.f + __expf(v1 - v0));
  const float w1 = 1.f - w0;
  if (l == 0) {
    e01[t] = i0 | (i1 << 8);
    w0f[t] = w0;
    w1f[t] = w1;
  }
  // out init: weighted down-proj biases
  const float4* bd0 = (const float4*)(bd + (size_t)i0 * HD);
  const float4* bd1 = (const float4*)(bd + (size_t)i1 * HD);
  float4* o4 = (float4*)(out + (size_t)t * HD);
  for (int i = 0; i < 4; ++i) {
    const int idx = l + 64 * i;
    float4 a = bd0[idx], b = bd1[idx];
    float4 r;
    r.x = w0 * a.x + w1 * b.x;
    r.y = w0 * a.y + w1 * b.y;
    r.z = w0 * a.z + w1 * b.z;
    r.w = w0 * a.w + w1 * b.w;
    o4[idx] = r;
  }
}

// ---------------- scan: counts, offsets, placement (one block) ----------------
__global__ __launch_bounds__(1024) void k_scan(const int* __restrict__ e01,
                                               const float* __restrict__ w0f,
                                               const float* __restrict__ w1f,
                                               int* __restrict__ cnt,
                                               int* __restrict__ off,
                                               int* __restrict__ gtok,
                                               float* __restrict__ gwt) {
  __shared__ int scnt[NEXPERT];
  __shared__ int soff[NEXPERT];
  __shared__ int scur[NEXPERT];
  const int t = threadIdx.x;
  if (t < NEXPERT) { scnt[t] = 0; scur[t] = 0; }
  __syncthreads();
  const int p = e01[t];
  const int e0 = p & 255, e1 = p >> 8;
  atomicAdd(&scnt[e0], 1);
  atomicAdd(&scnt[e1], 1);
  __syncthreads();
  if (t == 0) {
    int a = 0;
    for (int e = 0; e < NEXPERT; ++e) { soff[e] = a; off[e] = a; cnt[e] = scnt[e]; a += scnt[e]; }
  }
  __syncthreads();
  int s0 = atomicAdd(&scur[e0], 1);
  gtok[soff[e0] + s0] = t; gwt[soff[e0] + s0] = w0f[t];
  int s1 = atomicAdd(&scur[e1], 1);
  gtok[soff[e1] + s1] = t; gwt[soff[e1] + s1] = w1f[t];
}

// ---------------- GEMM1: barrier-free, no LDS. Block = 64 rows x 64 f2-cols; wave = 64x16 ----------------
// grid (32 ntiles, 16 mtiles, 16 experts); Wgu[e] is [K=1024][N=2048]
__global__ __launch_bounds__(256, 4) void k_gemm1(const unsigned short* __restrict__ Xbf,
                                                  const float* __restrict__ Wgu,
                                                  const float* __restrict__ bgu,
                                                  const int* __restrict__ cnt,
                                                  const int* __restrict__ off,
                                                  const int* __restrict__ gtok,
                                                  unsigned short* __restrict__ Gact) {
  const int e = blockIdx.z;
  const int Ne = cnt[e];
  const int mtile = blockIdx.y;
  if (mtile * 64 >= Ne) return;
  const int ntile = blockIdx.x;
  const int tid = threadIdx.x;
  const int lane = tid & 63;
  const int wv = tid >> 6;
  const int q = lane >> 4;
  const int fr = lane & 15;
  const int base = off[e] + mtile * 64;

  // A fragment base pointers (token gather folded in); frag layout m=fr, k=q*8+j
  const unsigned short* ap[4];
#pragma unroll
  for (int mi = 0; mi < 4; ++mi) {
    const int rloc = mi * 16 + fr;
    const int gs = base + ((mtile * 64 + rloc < Ne) ? rloc : 0);
    ap[mi] = Xbf + (size_t)gtok[gs] * HD + q * 8;
  }
  // B: col along lanes (n=fr), k = q*8+j along regs; direct from fp32 weights
  const int col = ntile * 64 + wv * 16 + fr;
  const float* bp = Wgu + (size_t)e * HD * F2D + (size_t)(q * 8) * F2D + col;

  short8 areg[2][4];
  float breg[2][8];
  f32x4 acc[4] = {};

#pragma unroll
  for (int s = 0; s < 2; ++s) {
#pragma unroll
    for (int mi = 0; mi < 4; ++mi) areg[s][mi] = *(const short8*)(ap[mi] + s * 32);
    const float* b = bp + (size_t)s * 32 * F2D;
#pragma unroll
    for (int j = 0; j < 8; ++j) breg[s][j] = b[(size_t)j * F2D];
  }

#pragma unroll 2
  for (int ks = 0; ks < 32; ++ks) {
    const int s = ks & 1;
    union { unsigned int u[4]; short8 s8; } uu;
    uu.u[0] = pk2(breg[s][0], breg[s][1]);
    uu.u[1] = pk2(breg[s][2], breg[s][3]);
    uu.u[2] = pk2(breg[s][4], breg[s][5]);
    uu.u[3] = pk2(breg[s][6], breg[s][7]);
    const short8 bfrag = uu.s8;
#pragma unroll
    for (int mi = 0; mi < 4; ++mi)
      acc[mi] = __builtin_amdgcn_mfma_f32_16x16x32_bf16(areg[s][mi], bfrag, acc[mi], 0, 0, 0);
    if (ks < 30) {
      const int kn = ks + 2;
#pragma unroll
      for (int mi = 0; mi < 4; ++mi) areg[s][mi] = *(const short8*)(ap[mi] + kn * 32);
      const float* b = bp + (size_t)kn * 32 * F2D;
#pragma unroll
      for (int j = 0; j < 8; ++j) breg[s][j] = b[(size_t)j * F2D];
    }
  }

  // epilogue: +bgu, de-interleave gate/up via lane-pair shuffle, activation, store bf16
  const float bias = bgu[(size_t)e * F2D + col];
#pragma unroll
  for (int mi = 0; mi < 4; ++mi) {
#pragma unroll
    for (int r = 0; r < 4; ++r) {
      const int srow = mi * 16 + q * 4 + r;       // row within tile (C layout: row=q*4+r)
      float v = acc[mi][r] + bias;
      float pv = __shfl_xor(v, 1);
      float gate = (lane & 1) ? pv : v;           // even f2-cols are gate, odd are up
      float up   = (lane & 1) ? v : pv;
      gate = fminf(gate, LIMIT_C);
      up = fminf(fmaxf(up, -LIMIT_C), LIMIT_C);
      float glu = gate / (1.f + __expf(-ALPHA_C * gate));
      float val = (up + 1.f) * glu;
      if (!(lane & 1) && (mtile * 64 + srow) < Ne)
        Gact[(size_t)(base + srow) * ED + (col >> 1)] = f2bf(val);
    }
  }
}

// ---------------- GEMM2: barrier-free, no LDS. Block = 64 rows x 64 h-cols ----------------
// grid (16 ntiles, 16 mtiles, 16 experts); Wd[e] is [K=1024][N=1024]
__global__ __launch_bounds__(256, 4) void k_gemm2(const unsigned short* __restrict__ Gact,
                                                  const float* __restrict__ Wd,
                                                  const int* __restrict__ cnt,
                                                  const int* __restrict__ off,
                                                  const int* __restrict__ gtok,
                                                  const float* __restrict__ gwt,
                                                  float* __restrict__ out) {
  const int e = blockIdx.z;
  const int Ne = cnt[e];
  const int mtile = blockIdx.y;
  if (mtile * 64 >= Ne) return;
  const int ntile = blockIdx.x;
  const int tid = threadIdx.x;
  const int lane = tid & 63;
  const int wv = tid >> 6;
  const int q = lane >> 4;
  const int fr = lane & 15;
  const int base = off[e] + mtile * 64;

  const unsigned short* ap[4];
#pragma unroll
  for (int mi = 0; mi < 4; ++mi)
    ap[mi] = Gact + (size_t)(base + mi * 16 + fr) * ED + q * 8;  // slack rows safe (GROWS)
  const int col = ntile * 64 + wv * 16 + fr;
  const float* bp = Wd + (size_t)e * ED * HD + (size_t)(q * 8) * HD + col;

  short8 areg[2][4];
  float breg[2][8];
  f32x4 acc[4] = {};

#pragma unroll
  for (int s = 0; s < 2; ++s) {
#pragma unroll
    for (int mi = 0; mi < 4; ++mi) areg[s][mi] = *(const short8*)(ap[mi] + s * 32);
    const float* b = bp + (size_t)s * 32 * HD;
#pragma unroll
    for (int j = 0; j < 8; ++j) breg[s][j] = b[(size_t)j * HD];
  }

#pragma unroll 2
  for (int ks = 0; ks < 32; ++ks) {
    const int s = ks & 1;
    union { unsigned int u[4]; short8 s8; } uu;
    uu.u[0] = pk2(breg[s][0], breg[s][1]);
    uu.u[1] = pk2(breg[s][2], breg[s][3]);
    uu.u[2] = pk2(breg[s][4], breg[s][5]);
    uu.u[3] = pk2(breg[s][6], breg[s][7]);
    const short8 bfrag = uu.s8;
#pragma unroll
    for (int mi = 0; mi < 4; ++mi)
      acc[mi] = __builtin_amdgcn_mfma_f32_16x16x32_bf16(areg[s][mi], bfrag, acc[mi], 0, 0, 0);
    if (ks < 30) {
      const int kn = ks + 2;
#pragma unroll
      for (int mi = 0; mi < 4; ++mi) areg[s][mi] = *(const short8*)(ap[mi] + kn * 32);
      const float* b = bp + (size_t)kn * 32 * HD;
#pragma unroll
      for (int j = 0; j < 8; ++j) breg[s][j] = b[(size_t)j * HD];
    }
  }

#pragma unroll
  for (int mi = 0; mi < 4; ++mi) {
#pragma unroll
    for (int r = 0; r < 4; ++r) {
      const int srow = mi * 16 + q * 4 + r;
      if ((mtile * 64 + srow) < Ne) {
        const int gsl = base + srow;
        const int tok = gtok[gsl];
        const float wt = gwt[gsl];
        atomicAdd(out + (size_t)tok * HD + col, wt * acc[mi][r]);
      }
    }
  }
}

extern "C" void kernel_launch(void* const* d_in, const int* in_sizes, int n_in,
                              void* d_out, int out_size, void* d_ws, size_t ws_size,
                              hipStream_t stream) {
  const float* x   = (const float*)d_in[0];
  const float* Wg  = (const float*)d_in[1];
  const float* bg  = (const float*)d_in[2];
  const float* Wgu = (const float*)d_in[3];
  const float* bgu = (const float*)d_in[4];
  const float* Wd  = (const float*)d_in[5];
  const float* bd  = (const float*)d_in[6];
  float* out = (float*)d_out;

  int* cnt = (int*)d_ws;                    // 16
  int* off = cnt + 16;                      // 16
  int* e01 = off + 16;                      // 1024
  float* w0f = (float*)(e01 + NT);          // 1024
  float* w1f = w0f + NT;                    // 1024
  int* gtok = (int*)(w1f + NT);             // GROWS
  float* gwt = (float*)(gtok + GROWS);      // GROWS
  unsigned short* Xbf = (unsigned short*)(gwt + GROWS);        // NT*HD bf16
  unsigned short* Gact = Xbf + (size_t)NT * HD;                // GROWS*ED bf16

  k_router<<<NT, 64, 0, stream>>>(x, Wg, bg, bd, e01, w0f, w1f, Xbf, out);
  k_scan<<<1, NT, 0, stream>>>(e01, w0f, w1f, cnt, off, gtok, gwt);
  k_gemm1<<<dim3(32, 16, NEXPERT), 256, 0, stream>>>(Xbf, Wgu, bgu, cnt, off, gtok, Gact);
  k_gemm2<<<dim3(16, 16, NEXPERT), 256, 0, stream>>>(Gact, Wd, cnt, off, gtok, gwt, out);
}

// Round 5
// 379.176 us; speedup vs baseline: 1.0702x; 1.0702x over previous
//
#include <hip/hip_runtime.h>
#include <hip/hip_bf16.h>

#define NT 1024     // tokens (B*S)
#define HD 1024     // hidden
#define ED 1024     // expert inner dim
#define F2D 2048    // 2*E (interleaved gate/up)
#define NEXPERT 16
#define GROWS 2304  // compacted rows (2048) + tile slack
#define ALPHA_C 1.702f
#define LIMIT_C 7.0f

typedef float f32x4 __attribute__((ext_vector_type(4)));
typedef short short8 __attribute__((ext_vector_type(8)));
typedef unsigned int u32x4 __attribute__((ext_vector_type(4)));

__device__ __forceinline__ unsigned short f2bf(float x) {
  union { float f; unsigned int u; } v; v.f = x;
  unsigned int r = v.u + 0x7FFFu + ((v.u >> 16) & 1u);
  return (unsigned short)(r >> 16);
}
__device__ __forceinline__ unsigned int pk2(float lo, float hi) {
  return (unsigned int)f2bf(lo) | ((unsigned int)f2bf(hi) << 16);
}
// async global->LDS, 16B per lane; LDS dest = wave-uniform base + lane*16
__device__ __forceinline__ void async16(const void* g, void* l) {
  __builtin_amdgcn_global_load_lds((const __attribute__((address_space(1))) void*)g,
                                   (__attribute__((address_space(3))) void*)l, 16, 0, 0);
}

// ---------------- router: fp32 logits, top-2, softmax; x->bf16; out = w0*bd[e0]+w1*bd[e1] ----------------
__global__ __launch_bounds__(64) void k_router(const float* __restrict__ x,
                                               const float* __restrict__ Wg,
                                               const float* __restrict__ bg,
                                               const float* __restrict__ bd,
                                               int* __restrict__ e01,
                                               float* __restrict__ w0f,
                                               float* __restrict__ w1f,
                                               unsigned short* __restrict__ Xbf,
                                               float* __restrict__ out) {
  const int t = blockIdx.x;
  const int l = threadIdx.x;
  const float4* x4 = (const float4*)(x + (size_t)t * HD);
  for (int i = 0; i < 4; ++i) {
    const int idx = l + 64 * i;
    float4 v = x4[idx];
    unsigned int a = pk2(v.x, v.y);
    unsigned int b = pk2(v.z, v.w);
    unsigned int* dst = (unsigned int*)(Xbf + (size_t)t * HD + idx * 4);
    dst[0] = a; dst[1] = b;
  }
  const int e = l & 15, qq = l >> 4;
  const float4* wg4 = (const float4*)(Wg + (size_t)e * HD);
  float s = 0.f;
  for (int j = 0; j < 64; ++j) {
    const int idx = qq + 4 * j;
    float4 a = x4[idx], b = wg4[idx];
    s += a.x * b.x + a.y * b.y + a.z * b.z + a.w * b.w;
  }
  s += __shfl_xor(s, 16);
  s += __shfl_xor(s, 32);
  const float logit = s + bg[e];  // valid in lanes 0..15
  float v0 = -1e30f, v1 = -1e30f; int i0 = 0, i1 = 0;
  for (int k = 0; k < 16; ++k) {
    float lv = __shfl(logit, k);
    if (lv > v0) { v1 = v0; i1 = i0; v0 = lv; i0 = k; }
    else if (lv > v1) { v1 = lv; i1 = k; }
  }
  const float w0 = 1.f / (1.f + __expf(v1 - v0));
  const float w1 = 1.f - w0;
  if (l == 0) {
    e01[t] = i0 | (i1 << 8);
    w0f[t] = w0;
    w1f[t] = w1;
  }
  const float4* bd0 = (const float4*)(bd + (size_t)i0 * HD);
  const float4* bd1 = (const float4*)(bd + (size_t)i1 * HD);
  float4* o4 = (float4*)(out + (size_t)t * HD);
  for (int i = 0; i < 4; ++i) {
    const int idx = l + 64 * i;
    float4 a = bd0[idx], b = bd1[idx];
    float4 r;
    r.x = w0 * a.x + w1 * b.x;
    r.y = w0 * a.y + w1 * b.y;
    r.z = w0 * a.z + w1 * b.z;
    r.w = w0 * a.w + w1 * b.w;
    o4[idx] = r;
  }
}

// ---------------- scan: counts, offsets, placement (one block) ----------------
__global__ __launch_bounds__(1024) void k_scan(const int* __restrict__ e01,
                                               const float* __restrict__ w0f,
                                               const float* __restrict__ w1f,
                                               int* __restrict__ cnt,
                                               int* __restrict__ off,
                                               int* __restrict__ gtok,
                                               float* __restrict__ gwt) {
  __shared__ int scnt[NEXPERT];
  __shared__ int soff[NEXPERT];
  __shared__ int scur[NEXPERT];
  const int t = threadIdx.x;
  if (t < NEXPERT) { scnt[t] = 0; scur[t] = 0; }
  __syncthreads();
  const int p = e01[t];
  const int e0 = p & 255, e1 = p >> 8;
  atomicAdd(&scnt[e0], 1);
  atomicAdd(&scnt[e1], 1);
  __syncthreads();
  if (t == 0) {
    int a = 0;
    for (int e = 0; e < NEXPERT; ++e) { soff[e] = a; off[e] = a; cnt[e] = scnt[e]; a += scnt[e]; }
  }
  __syncthreads();
  int s0 = atomicAdd(&scur[e0], 1);
  gtok[soff[e0] + s0] = t; gwt[soff[e0] + s0] = w0f[t];
  int s1 = atomicAdd(&scur[e1], 1);
  gtok[soff[e1] + s1] = t; gwt[soff[e1] + s1] = w1f[t];
}

// ---------------- GEMM1: block 64Mx256N, BK=32, dbuf LDS, full-row coalesced B stream ----------------
// grid (8 ntiles, 16 mtiles, 16 experts); Wgu[e] is [K=1024][N=2048]
#define BST1 260   // Blds row stride (dwords): 256 + 4 pad
__global__ __launch_bounds__(256, 2) void k_gemm1(const unsigned short* __restrict__ Xbf,
                                                  const float* __restrict__ Wgu,
                                                  const float* __restrict__ bgu,
                                                  const int* __restrict__ cnt,
                                                  const int* __restrict__ off,
                                                  const int* __restrict__ gtok,
                                                  unsigned short* __restrict__ Gact) {
  const int e = blockIdx.z;
  const int Ne = cnt[e];
  const int mtile = blockIdx.y;
  if (mtile * 64 >= Ne) return;
  const int ntile = blockIdx.x;
  const int tid = threadIdx.x;
  const int lane = tid & 63;
  const int wv = tid >> 6;
  const int q = lane >> 4;
  const int fr = lane & 15;
  const int base = off[e] + mtile * 64;

  __shared__ unsigned short Alds[2][64 * 32];   // [buf][row*32 + k], 64B rows
  __shared__ unsigned int Blds[2][16 * BST1];   // [buf][kpair*BST1 + n]

  // A staging: wave wv stages rows wv*16 + (lane>>2), 16B chunk lane&3
  const int arow = wv * 16 + (lane >> 2);
  const int ags = base + (((mtile * 64 + arow) < Ne) ? arow : 0);
  const unsigned short* agp = Xbf + (size_t)gtok[ags] * HD + (lane & 3) * 8;
  const int aofs = wv * 512;  // shorts: 16 rows * 32 shorts/row

  // B staging: thread loads 8 full-row dwordx4: row = wv*8 + j, col = lane*4
  const float* Wb = Wgu + (size_t)e * HD * F2D + (size_t)(wv * 8) * F2D + ntile * 256 + lane * 4;

  f32x4 acc[4][4] = {};
  float4 br[8];

  // prologue: stage tile 0
#pragma unroll
  for (int j = 0; j < 8; ++j) br[j] = *(const float4*)(Wb + (size_t)j * F2D);
  async16(agp, Alds[0] + aofs);
#pragma unroll
  for (int p = 0; p < 4; ++p) {
    u32x4 pkv;
    pkv[0] = pk2(br[2 * p].x, br[2 * p + 1].x);
    pkv[1] = pk2(br[2 * p].y, br[2 * p + 1].y);
    pkv[2] = pk2(br[2 * p].z, br[2 * p + 1].z);
    pkv[3] = pk2(br[2 * p].w, br[2 * p + 1].w);
    *(u32x4*)(Blds[0] + (wv * 4 + p) * BST1 + lane * 4) = pkv;
  }
  __syncthreads();

  for (int ks = 0; ks < 32; ++ks) {
    const int cur = ks & 1, nxt = cur ^ 1;
    const bool more = (ks + 1) < 32;
    if (more) {
      const float* bp = Wb + (size_t)(ks + 1) * 32 * F2D;
#pragma unroll
      for (int j = 0; j < 8; ++j) br[j] = *(const float4*)(bp + (size_t)j * F2D);
      async16(agp + (ks + 1) * 32, Alds[nxt] + aofs);
    }
    short8 af[4], bfr[4];
#pragma unroll
    for (int mi = 0; mi < 4; ++mi)
      af[mi] = *(const short8*)(Alds[cur] + (mi * 16 + fr) * 32 + q * 8);
#pragma unroll
    for (int ni = 0; ni < 4; ++ni) {
      const unsigned int* p = Blds[cur] + q * 4 * BST1 + wv * 64 + ni * 16 + fr;
      union { unsigned int u[4]; short8 s; } uu;
      uu.u[0] = p[0]; uu.u[1] = p[BST1]; uu.u[2] = p[2 * BST1]; uu.u[3] = p[3 * BST1];
      bfr[ni] = uu.s;
    }
#pragma unroll
    for (int mi = 0; mi < 4; ++mi)
#pragma unroll
      for (int ni = 0; ni < 4; ++ni)
        acc[mi][ni] = __builtin_amdgcn_mfma_f32_16x16x32_bf16(af[mi], bfr[ni], acc[mi][ni], 0, 0, 0);
    if (more) {
#pragma unroll
      for (int p = 0; p < 4; ++p) {
        u32x4 pkv;
        pkv[0] = pk2(br[2 * p].x, br[2 * p + 1].x);
        pkv[1] = pk2(br[2 * p].y, br[2 * p + 1].y);
        pkv[2] = pk2(br[2 * p].z, br[2 * p + 1].z);
        pkv[3] = pk2(br[2 * p].w, br[2 * p + 1].w);
        *(u32x4*)(Blds[nxt] + (wv * 4 + p) * BST1 + lane * 4) = pkv;
      }
    }
    __syncthreads();
  }

  // epilogue: +bgu, de-interleave gate/up via lane-pair shuffle, activation, store bf16
  const float* bguE = bgu + (size_t)e * F2D + ntile * 256;
#pragma unroll
  for (int mi = 0; mi < 4; ++mi) {
#pragma unroll
    for (int ni = 0; ni < 4; ++ni) {
      const int col = wv * 64 + ni * 16 + fr;
      const float bias = bguE[col];
#pragma unroll
      for (int r = 0; r < 4; ++r) {
        const int srow = mi * 16 + q * 4 + r;
        float v = acc[mi][ni][r] + bias;
        float pv = __shfl_xor(v, 1);
        float gate = (lane & 1) ? pv : v;   // even f2-cols are gate, odd are up
        float up   = (lane & 1) ? v : pv;
        gate = fminf(gate, LIMIT_C);
        up = fminf(fmaxf(up, -LIMIT_C), LIMIT_C);
        float glu = gate / (1.f + __expf(-ALPHA_C * gate));
        float val = (up + 1.f) * glu;
        if (!(lane & 1) && (mtile * 64 + srow) < Ne)
          Gact[(size_t)(base + srow) * ED + ((ntile * 256 + col) >> 1)] = f2bf(val);
      }
    }
  }
}

// ---------------- GEMM2: block 64Mx128N, BK=32, dbuf LDS, half-row coalesced B stream ----------------
// grid (8 ntiles, 16 mtiles, 16 experts); Wd[e] is [K=1024][N=1024]
#define BST2 132   // Blds row stride (dwords): 128 + 4 pad
__global__ __launch_bounds__(256, 2) void k_gemm2(const unsigned short* __restrict__ Gact,
                                                  const float* __restrict__ Wd,
                                                  const int* __restrict__ cnt,
                                                  const int* __restrict__ off,
                                                  const int* __restrict__ gtok,
                                                  const float* __restrict__ gwt,
                                                  float* __restrict__ out) {
  const int e = blockIdx.z;
  const int Ne = cnt[e];
  const int mtile = blockIdx.y;
  if (mtile * 64 >= Ne) return;
  const int ntile = blockIdx.x;
  const int tid = threadIdx.x;
  const int lane = tid & 63;
  const int wv = tid >> 6;
  const int q = lane >> 4;
  const int fr = lane & 15;
  const int base = off[e] + mtile * 64;

  __shared__ unsigned short Alds[2][64 * 32];
  __shared__ unsigned int Blds[2][16 * BST2];

  const int arow = wv * 16 + (lane >> 2);
  const unsigned short* agp = Gact + (size_t)(base + arow) * ED + (lane & 3) * 8;  // slack rows safe
  const int aofs = wv * 512;  // shorts: 16 rows * 32 shorts/row

  // B staging: thread loads 4 dwordx4: row = wv*8 + (lane>>5)*4 + j (j=0..3), col = (lane&31)*4
  const int brow0 = wv * 8 + (lane >> 5) * 4;
  const int bcol = (lane & 31) * 4;
  const float* Wb = Wd + (size_t)e * ED * HD + (size_t)brow0 * HD + ntile * 128 + bcol;

  f32x4 acc[4][2] = {};
  float4 br[4];

#pragma unroll
  for (int j = 0; j < 4; ++j) br[j] = *(const float4*)(Wb + (size_t)j * HD);
  async16(agp, Alds[0] + aofs);
#pragma unroll
  for (int p = 0; p < 2; ++p) {
    u32x4 pkv;
    pkv[0] = pk2(br[2 * p].x, br[2 * p + 1].x);
    pkv[1] = pk2(br[2 * p].y, br[2 * p + 1].y);
    pkv[2] = pk2(br[2 * p].z, br[2 * p + 1].z);
    pkv[3] = pk2(br[2 * p].w, br[2 * p + 1].w);
    *(u32x4*)(Blds[0] + (brow0 / 2 + p) * BST2 + bcol) = pkv;
  }
  __syncthreads();

  for (int ks = 0; ks < 32; ++ks) {
    const int cur = ks & 1, nxt = cur ^ 1;
    const bool more = (ks + 1) < 32;
    if (more) {
      const float* bp = Wb + (size_t)(ks + 1) * 32 * HD;
#pragma unroll
      for (int j = 0; j < 4; ++j) br[j] = *(const float4*)(bp + (size_t)j * HD);
      async16(agp + (ks + 1) * 32, Alds[nxt] + aofs);
    }
    short8 af[4], bfr[2];
#pragma unroll
    for (int mi = 0; mi < 4; ++mi)
      af[mi] = *(const short8*)(Alds[cur] + (mi * 16 + fr) * 32 + q * 8);
#pragma unroll
    for (int ni = 0; ni < 2; ++ni) {
      const unsigned int* p = Blds[cur] + q * 4 * BST2 + wv * 32 + ni * 16 + fr;
      union { unsigned int u[4]; short8 s; } uu;
      uu.u[0] = p[0]; uu.u[1] = p[BST2]; uu.u[2] = p[2 * BST2]; uu.u[3] = p[3 * BST2];
      bfr[ni] = uu.s;
    }
#pragma unroll
    for (int mi = 0; mi < 4; ++mi)
#pragma unroll
      for (int ni = 0; ni < 2; ++ni)
        acc[mi][ni] = __builtin_amdgcn_mfma_f32_16x16x32_bf16(af[mi], bfr[ni], acc[mi][ni], 0, 0, 0);
    if (more) {
#pragma unroll
      for (int p = 0; p < 2; ++p) {
        u32x4 pkv;
        pkv[0] = pk2(br[2 * p].x, br[2 * p + 1].x);
        pkv[1] = pk2(br[2 * p].y, br[2 * p + 1].y);
        pkv[2] = pk2(br[2 * p].z, br[2 * p + 1].z);
        pkv[3] = pk2(br[2 * p].w, br[2 * p + 1].w);
        *(u32x4*)(Blds[nxt] + (brow0 / 2 + p) * BST2 + bcol) = pkv;
      }
    }
    __syncthreads();
  }

#pragma unroll
  for (int mi = 0; mi < 4; ++mi) {
#pragma unroll
    for (int r = 0; r < 4; ++r) {
      const int srow = mi * 16 + q * 4 + r;
      if ((mtile * 64 + srow) < Ne) {
        const int gsl = base + srow;
        const int tok = gtok[gsl];
        const float wt = gwt[gsl];
        float* op = out + (size_t)tok * HD + ntile * 128;
#pragma unroll
        for (int ni = 0; ni < 2; ++ni) {
          const int col = wv * 32 + ni * 16 + fr;
          atomicAdd(op + col, wt * acc[mi][ni][r]);
        }
      }
    }
  }
}

extern "C" void kernel_launch(void* const* d_in, const int* in_sizes, int n_in,
                              void* d_out, int out_size, void* d_ws, size_t ws_size,
                              hipStream_t stream) {
  const float* x   = (const float*)d_in[0];
  const float* Wg  = (const float*)d_in[1];
  const float* bg  = (const float*)d_in[2];
  const float* Wgu = (const float*)d_in[3];
  const float* bgu = (const float*)d_in[4];
  const float* Wd  = (const float*)d_in[5];
  const float* bd  = (const float*)d_in[6];
  float* out = (float*)d_out;

  int* cnt = (int*)d_ws;                    // 16
  int* off = cnt + 16;                      // 16
  int* e01 = off + 16;                      // 1024
  float* w0f = (float*)(e01 + NT);          // 1024
  float* w1f = w0f + NT;                    // 1024
  int* gtok = (int*)(w1f + NT);             // GROWS
  float* gwt = (float*)(gtok + GROWS);      // GROWS
  unsigned short* Xbf = (unsigned short*)(gwt + GROWS);        // NT*HD bf16
  unsigned short* Gact = Xbf + (size_t)NT * HD;                // GROWS*ED bf16

  k_router<<<NT, 64, 0, stream>>>(x, Wg, bg, bd, e01, w0f, w1f, Xbf, out);
  k_scan<<<1, NT, 0, stream>>>(e01, w0f, w1f, cnt, off, gtok, gwt);
  k_gemm1<<<dim3(8, 16, NEXPERT), 256, 0, stream>>>(Xbf, Wgu, bgu, cnt, off, gtok, Gact);
  k_gemm2<<<dim3(8, 16, NEXPERT), 256, 0, stream>>>(Gact, Wd, cnt, off, gtok, gwt, out);
}

// Round 6
// 341.545 us; speedup vs baseline: 1.1881x; 1.1102x over previous
//
#include <hip/hip_runtime.h>
#include <hip/hip_bf16.h>

#define NT 1024     // tokens (B*S)
#define HD 1024     // hidden
#define ED 1024     // expert inner dim
#define F2D 2048    // 2*E (interleaved gate/up)
#define NEXPERT 16
#define GROWS 2304  // compacted rows (2048) + tile slack (gemm2 reads up to base+255 <= 2303)
#define ALPHA_C 1.702f
#define LIMIT_C 7.0f

typedef float f32x4 __attribute__((ext_vector_type(4)));
typedef float fv4 __attribute__((ext_vector_type(4)));
typedef short short8 __attribute__((ext_vector_type(8)));
typedef unsigned int u32x4 __attribute__((ext_vector_type(4)));

__device__ __forceinline__ unsigned short f2bf(float x) {
  union { float f; unsigned int u; } v; v.f = x;
  unsigned int r = v.u + 0x7FFFu + ((v.u >> 16) & 1u);
  return (unsigned short)(r >> 16);
}
__device__ __forceinline__ unsigned int pk2(float lo, float hi) {
  return (unsigned int)f2bf(lo) | ((unsigned int)f2bf(hi) << 16);
}
// non-temporal float4 load (weights: stream, don't cache)
__device__ __forceinline__ fv4 ldnt4(const float* p) {
  return __builtin_nontemporal_load((const fv4*)p);
}
// async global->LDS, 16B per lane; LDS dest = wave-uniform base + lane*16
__device__ __forceinline__ void async16(const void* g, void* l) {
  __builtin_amdgcn_global_load_lds((const __attribute__((address_space(1))) void*)g,
                                   (__attribute__((address_space(3))) void*)l, 16, 0, 0);
}

// ---------------- router: fp32 logits, top-2, softmax; x->bf16; out = w0*bd[e0]+w1*bd[e1] ----------------
__global__ __launch_bounds__(64) void k_router(const float* __restrict__ x,
                                               const float* __restrict__ Wg,
                                               const float* __restrict__ bg,
                                               const float* __restrict__ bd,
                                               int* __restrict__ e01,
                                               float* __restrict__ w0f,
                                               float* __restrict__ w1f,
                                               unsigned short* __restrict__ Xbf,
                                               float* __restrict__ out) {
  const int t = blockIdx.x;
  const int l = threadIdx.x;
  const float4* x4 = (const float4*)(x + (size_t)t * HD);
  for (int i = 0; i < 4; ++i) {
    const int idx = l + 64 * i;
    float4 v = x4[idx];
    unsigned int a = pk2(v.x, v.y);
    unsigned int b = pk2(v.z, v.w);
    unsigned int* dst = (unsigned int*)(Xbf + (size_t)t * HD + idx * 4);
    dst[0] = a; dst[1] = b;
  }
  const int e = l & 15, qq = l >> 4;
  const float4* wg4 = (const float4*)(Wg + (size_t)e * HD);
  float s = 0.f;
  for (int j = 0; j < 64; ++j) {
    const int idx = qq + 4 * j;
    float4 a = x4[idx], b = wg4[idx];
    s += a.x * b.x + a.y * b.y + a.z * b.z + a.w * b.w;
  }
  s += __shfl_xor(s, 16);
  s += __shfl_xor(s, 32);
  const float logit = s + bg[e];  // valid in lanes 0..15
  float v0 = -1e30f, v1 = -1e30f; int i0 = 0, i1 = 0;
  for (int k = 0; k < 16; ++k) {
    float lv = __shfl(logit, k);
    if (lv > v0) { v1 = v0; i1 = i0; v0 = lv; i0 = k; }
    else if (lv > v1) { v1 = lv; i1 = k; }
  }
  const float w0 = 1.f / (1.f + __expf(v1 - v0));
  const float w1 = 1.f - w0;
  if (l == 0) {
    e01[t] = i0 | (i1 << 8);
    w0f[t] = w0;
    w1f[t] = w1;
  }
  const float4* bd0 = (const float4*)(bd + (size_t)i0 * HD);
  const float4* bd1 = (const float4*)(bd + (size_t)i1 * HD);
  float4* o4 = (float4*)(out + (size_t)t * HD);
  for (int i = 0; i < 4; ++i) {
    const int idx = l + 64 * i;
    float4 a = bd0[idx], b = bd1[idx];
    float4 r;
    r.x = w0 * a.x + w1 * b.x;
    r.y = w0 * a.y + w1 * b.y;
    r.z = w0 * a.z + w1 * b.z;
    r.w = w0 * a.w + w1 * b.w;
    o4[idx] = r;
  }
}

// ---------------- scan: counts, offsets, placement (one block) ----------------
__global__ __launch_bounds__(1024) void k_scan(const int* __restrict__ e01,
                                               const float* __restrict__ w0f,
                                               const float* __restrict__ w1f,
                                               int* __restrict__ cnt,
                                               int* __restrict__ off,
                                               int* __restrict__ gtok,
                                               float* __restrict__ gwt) {
  __shared__ int scnt[NEXPERT];
  __shared__ int soff[NEXPERT];
  __shared__ int scur[NEXPERT];
  const int t = threadIdx.x;
  if (t < NEXPERT) { scnt[t] = 0; scur[t] = 0; }
  __syncthreads();
  const int p = e01[t];
  const int e0 = p & 255, e1 = p >> 8;
  atomicAdd(&scnt[e0], 1);
  atomicAdd(&scnt[e1], 1);
  __syncthreads();
  if (t == 0) {
    int a = 0;
    for (int e = 0; e < NEXPERT; ++e) { soff[e] = a; off[e] = a; cnt[e] = scnt[e]; a += scnt[e]; }
  }
  __syncthreads();
  int s0 = atomicAdd(&scur[e0], 1);
  gtok[soff[e0] + s0] = t; gwt[soff[e0] + s0] = w0f[t];
  int s1 = atomicAdd(&scur[e1], 1);
  gtok[soff[e1] + s1] = t; gwt[soff[e1] + s1] = w1f[t];
}

// ---------------- GEMM1: block 256M x 128N, 512 thr (8 waves 4mx2n), BK=32, dbuf, weights read ONCE ----------------
// grid (16 ntiles, 2 mtiles, 16 experts); Wgu[e] is [K=1024][N=2048]
#define BSTG1 132   // Blds row stride in dwords (128 + 4 pad)
__global__ __launch_bounds__(512, 2) void k_gemm1(const unsigned short* __restrict__ Xbf,
                                                  const float* __restrict__ Wgu,
                                                  const float* __restrict__ bgu,
                                                  const int* __restrict__ cnt,
                                                  const int* __restrict__ off,
                                                  const int* __restrict__ gtok,
                                                  unsigned short* __restrict__ Gact) {
  const int e = blockIdx.z;
  const int Ne = cnt[e];
  const int mtile = blockIdx.y;
  if (mtile * 256 >= Ne) return;
  const int ntile = blockIdx.x;
  const int tid = threadIdx.x;          // 0..511
  const int lane = tid & 63;
  const int wv = tid >> 6;              // 0..7
  const int wm = wv >> 1;               // 0..3  (M 64-slice)
  const int wn = wv & 1;                // 0..1  (N 64-slice)
  const int q = lane >> 4;
  const int fr = lane & 15;
  const int base = off[e] + mtile * 256;

  __shared__ unsigned short Alds[2][256 * 32];   // [buf][row*32 + k]  (64B rows)  32 KB
  __shared__ unsigned int Blds[2][16 * BSTG1];   // [buf][kpair*BSTG1 + n]        ~17 KB

  // A staging: wave wv stages rows wv*32 + (lane>>2) and +16; chunk = lane&3
  const int ar0 = wv * 32 + (lane >> 2);
  const int ar1 = ar0 + 16;
  const int ags0 = base + (((mtile * 256 + ar0) < Ne) ? ar0 : 0);
  const int ags1 = base + (((mtile * 256 + ar1) < Ne) ? ar1 : 0);
  const unsigned short* agp0 = Xbf + (size_t)gtok[ags0] * HD + (lane & 3) * 8;
  const unsigned short* agp1 = Xbf + (size_t)gtok[ags1] * HD + (lane & 3) * 8;
  const int aofs = wv * 1024;  // shorts: 32 rows * 32 shorts

  // B staging: thread -> kpair p2 = tid>>5 (0..15), colgrp bc = tid&31 (4 cols each)
  const int p2 = tid >> 5;
  const int bc = tid & 31;
  const float* Wb = Wgu + (size_t)e * HD * F2D + (size_t)(2 * p2) * F2D + ntile * 128 + bc * 4;

  f32x4 acc[4][4] = {};
  fv4 b0, b1;

  // prologue: stage tile 0
  b0 = ldnt4(Wb);
  b1 = ldnt4(Wb + F2D);
  async16(agp0, Alds[0] + aofs);
  async16(agp1, Alds[0] + aofs + 512);
  {
    u32x4 pkv;
    pkv[0] = pk2(b0[0], b1[0]); pkv[1] = pk2(b0[1], b1[1]);
    pkv[2] = pk2(b0[2], b1[2]); pkv[3] = pk2(b0[3], b1[3]);
    *(u32x4*)(Blds[0] + p2 * BSTG1 + bc * 4) = pkv;
  }
  __syncthreads();

  for (int ks = 0; ks < 32; ++ks) {
    const int cur = ks & 1, nxt = cur ^ 1;
    const bool more = (ks + 1) < 32;
    if (more) {
      const float* bp = Wb + (size_t)(ks + 1) * 32 * F2D;
      b0 = ldnt4(bp);
      b1 = ldnt4(bp + F2D);
      async16(agp0 + (ks + 1) * 32, Alds[nxt] + aofs);
      async16(agp1 + (ks + 1) * 32, Alds[nxt] + aofs + 512);
    }
    short8 af[4], bfr[4];
#pragma unroll
    for (int mi = 0; mi < 4; ++mi)
      af[mi] = *(const short8*)(Alds[cur] + (wm * 64 + mi * 16 + fr) * 32 + q * 8);
#pragma unroll
    for (int ni = 0; ni < 4; ++ni) {
      const unsigned int* p = Blds[cur] + (q * 4) * BSTG1 + wn * 64 + ni * 16 + fr;
      union { unsigned int u[4]; short8 s; } uu;
      uu.u[0] = p[0]; uu.u[1] = p[BSTG1]; uu.u[2] = p[2 * BSTG1]; uu.u[3] = p[3 * BSTG1];
      bfr[ni] = uu.s;
    }
#pragma unroll
    for (int mi = 0; mi < 4; ++mi)
#pragma unroll
      for (int ni = 0; ni < 4; ++ni)
        acc[mi][ni] = __builtin_amdgcn_mfma_f32_16x16x32_bf16(af[mi], bfr[ni], acc[mi][ni], 0, 0, 0);
    if (more) {
      u32x4 pkv;
      pkv[0] = pk2(b0[0], b1[0]); pkv[1] = pk2(b0[1], b1[1]);
      pkv[2] = pk2(b0[2], b1[2]); pkv[3] = pk2(b0[3], b1[3]);
      *(u32x4*)(Blds[nxt] + p2 * BSTG1 + bc * 4) = pkv;
    }
    __syncthreads();
  }

  // epilogue: +bgu, de-interleave gate/up via lane-pair shuffle, activation, store bf16
  const float* bguE = bgu + (size_t)e * F2D + ntile * 128;
#pragma unroll
  for (int mi = 0; mi < 4; ++mi) {
#pragma unroll
    for (int ni = 0; ni < 4; ++ni) {
      const int coll = wn * 64 + ni * 16 + fr;
      const float bias = bguE[coll];
#pragma unroll
      for (int r = 0; r < 4; ++r) {
        const int srow = wm * 64 + mi * 16 + q * 4 + r;
        float v = acc[mi][ni][r] + bias;
        float pv = __shfl_xor(v, 1);
        float gate = (lane & 1) ? pv : v;   // even f2-cols are gate, odd are up
        float up   = (lane & 1) ? v : pv;
        gate = fminf(gate, LIMIT_C);
        up = fminf(fmaxf(up, -LIMIT_C), LIMIT_C);
        float glu = gate / (1.f + __expf(-ALPHA_C * gate));
        float val = (up + 1.f) * glu;
        if (!(lane & 1) && (mtile * 256 + srow) < Ne)
          Gact[(size_t)(base + srow) * ED + ((ntile * 128 + coll) >> 1)] = f2bf(val);
      }
    }
  }
}

// ---------------- GEMM2: block 256M x 64N, 256 thr (4 waves, M-split), BK=32, dbuf, Wd read ONCE ----------------
// grid (16 ntiles, 2 mtiles, 16 experts); Wd[e] is [K=1024][N=1024]
#define BSTG2 68   // Blds row stride in dwords (64 + 4 pad)
__global__ __launch_bounds__(256, 2) void k_gemm2(const unsigned short* __restrict__ Gact,
                                                  const float* __restrict__ Wd,
                                                  const int* __restrict__ cnt,
                                                  const int* __restrict__ off,
                                                  const int* __restrict__ gtok,
                                                  const float* __restrict__ gwt,
                                                  float* __restrict__ out) {
  const int e = blockIdx.z;
  const int Ne = cnt[e];
  const int mtile = blockIdx.y;
  if (mtile * 256 >= Ne) return;
  const int ntile = blockIdx.x;
  const int tid = threadIdx.x;          // 0..255
  const int lane = tid & 63;
  const int wv = tid >> 6;              // 0..3 (M 64-slice; N full 64)
  const int q = lane >> 4;
  const int fr = lane & 15;
  const int base = off[e] + mtile * 256;

  __shared__ unsigned short Alds[2][256 * 32];   // 32 KB
  __shared__ unsigned int Blds[2][16 * BSTG2];   // ~8.7 KB

  // A staging: wave wv stages rows wv*64 + j*16 + (lane>>2), j=0..3 (rows base+0..255 < GROWS: safe)
  const int arb = wv * 64 + (lane >> 2);
  const unsigned short* agp = Gact + (size_t)(base + arb) * ED + (lane & 3) * 8;
  const int aofs = wv * 2048;  // shorts: 64 rows * 32 shorts

  // B staging: thread -> kpair p2 = tid>>4 (0..15), colgrp bc = tid&15 (4 cols each)
  const int p2 = tid >> 4;
  const int bc = tid & 15;
  const float* Wb = Wd + (size_t)e * ED * HD + (size_t)(2 * p2) * HD + ntile * 64 + bc * 4;

  f32x4 acc[4][4] = {};
  fv4 b0, b1;

  b0 = ldnt4(Wb);
  b1 = ldnt4(Wb + HD);
#pragma unroll
  for (int j = 0; j < 4; ++j)
    async16(agp + (size_t)j * 16 * ED, Alds[0] + aofs + j * 512);
  {
    u32x4 pkv;
    pkv[0] = pk2(b0[0], b1[0]); pkv[1] = pk2(b0[1], b1[1]);
    pkv[2] = pk2(b0[2], b1[2]); pkv[3] = pk2(b0[3], b1[3]);
    *(u32x4*)(Blds[0] + p2 * BSTG2 + bc * 4) = pkv;
  }
  __syncthreads();

  for (int ks = 0; ks < 32; ++ks) {
    const int cur = ks & 1, nxt = cur ^ 1;
    const bool more = (ks + 1) < 32;
    if (more) {
      const float* bp = Wb + (size_t)(ks + 1) * 32 * HD;
      b0 = ldnt4(bp);
      b1 = ldnt4(bp + HD);
#pragma unroll
      for (int j = 0; j < 4; ++j)
        async16(agp + (ks + 1) * 32 + (size_t)j * 16 * ED, Alds[nxt] + aofs + j * 512);
    }
    short8 af[4], bfr[4];
#pragma unroll
    for (int mi = 0; mi < 4; ++mi)
      af[mi] = *(const short8*)(Alds[cur] + (wv * 64 + mi * 16 + fr) * 32 + q * 8);
#pragma unroll
    for (int ni = 0; ni < 4; ++ni) {
      const unsigned int* p = Blds[cur] + (q * 4) * BSTG2 + ni * 16 + fr;
      union { unsigned int u[4]; short8 s; } uu;
      uu.u[0] = p[0]; uu.u[1] = p[BSTG2]; uu.u[2] = p[2 * BSTG2]; uu.u[3] = p[3 * BSTG2];
      bfr[ni] = uu.s;
    }
#pragma unroll
    for (int mi = 0; mi < 4; ++mi)
#pragma unroll
      for (int ni = 0; ni < 4; ++ni)
        acc[mi][ni] = __builtin_amdgcn_mfma_f32_16x16x32_bf16(af[mi], bfr[ni], acc[mi][ni], 0, 0, 0);
    if (more) {
      u32x4 pkv;
      pkv[0] = pk2(b0[0], b1[0]); pkv[1] = pk2(b0[1], b1[1]);
      pkv[2] = pk2(b0[2], b1[2]); pkv[3] = pk2(b0[3], b1[3]);
      *(u32x4*)(Blds[nxt] + p2 * BSTG2 + bc * 4) = pkv;
    }
    __syncthreads();
  }

#pragma unroll
  for (int mi = 0; mi < 4; ++mi) {
#pragma unroll
    for (int r = 0; r < 4; ++r) {
      const int srow = wv * 64 + mi * 16 + q * 4 + r;
      if ((mtile * 256 + srow) < Ne) {
        const int gsl = base + srow;
        const int tok = gtok[gsl];
        const float wt = gwt[gsl];
        float* op = out + (size_t)tok * HD + ntile * 64;
#pragma unroll
        for (int ni = 0; ni < 4; ++ni) {
          const int col = ni * 16 + fr;
          atomicAdd(op + col, wt * acc[mi][ni][r]);
        }
      }
    }
  }
}

extern "C" void kernel_launch(void* const* d_in, const int* in_sizes, int n_in,
                              void* d_out, int out_size, void* d_ws, size_t ws_size,
                              hipStream_t stream) {
  const float* x   = (const float*)d_in[0];
  const float* Wg  = (const float*)d_in[1];
  const float* bg  = (const float*)d_in[2];
  const float* Wgu = (const float*)d_in[3];
  const float* bgu = (const float*)d_in[4];
  const float* Wd  = (const float*)d_in[5];
  const float* bd  = (const float*)d_in[6];
  float* out = (float*)d_out;

  int* cnt = (int*)d_ws;                    // 16
  int* off = cnt + 16;                      // 16
  int* e01 = off + 16;                      // 1024
  float* w0f = (float*)(e01 + NT);          // 1024
  float* w1f = w0f + NT;                    // 1024
  int* gtok = (int*)(w1f + NT);             // GROWS
  float* gwt = (float*)(gtok + GROWS);      // GROWS
  unsigned short* Xbf = (unsigned short*)(gwt + GROWS);        // NT*HD bf16
  unsigned short* Gact = Xbf + (size_t)NT * HD;                // GROWS*ED bf16

  k_router<<<NT, 64, 0, stream>>>(x, Wg, bg, bd, e01, w0f, w1f, Xbf, out);
  k_scan<<<1, NT, 0, stream>>>(e01, w0f, w1f, cnt, off, gtok, gwt);
  k_gemm1<<<dim3(16, 2, NEXPERT), 512, 0, stream>>>(Xbf, Wgu, bgu, cnt, off, gtok, Gact);
  k_gemm2<<<dim3(16, 2, NEXPERT), 256, 0, stream>>>(Gact, Wd, cnt, off, gtok, gwt, out);
}